// Round 1
// baseline (1055.027 us; speedup 1.0000x reference)
//
#include <hip/hip_runtime.h>
#include <hip/hip_bf16.h>

typedef float fx4 __attribute__((ext_vector_type(4)));
typedef __bf16 bf16x8 __attribute__((ext_vector_type(8)));

#define NB 32
#define NH 16
#define NN 512
#define ND 64

// One block handles (b,h, 32-row q-block). 4 waves, 256 threads.
// Wave w owns score columns [w*128, w*128+128) for QK^T, and context
// sub-tile (rt = w>>1, d-cols (w&1)*32..+32) for PV.
__global__ __launch_bounds__(256, 2)
void attn_fused(const float* __restrict__ Q,
                const float* __restrict__ K,
                const float* __restrict__ V,
                const int*   __restrict__ pos_ids,
                const float* __restrict__ pkt,
                const float* __restrict__ pvt,
                float* __restrict__ ctx_out,
                float* __restrict__ attn_out)
{
    // P: 32 q-rows x 512 cols bf16. Row stride 520 -> 1040B (16B aligned, bank-staggered).
    __shared__ alignas(16) __bf16 Plds[32][520];
    // V' transposed chunk: [d=64][n=64], stride 72 -> 144B rows (16B aligned).
    __shared__ alignas(16) __bf16 vt[64][72];
    __shared__ alignas(16) float redA[32][4];
    __shared__ alignas(16) float redB[32][4];

    const int bid = blockIdx.x;
    // Bijective XCD swizzle: 16 q-blocks of the same (b,h) land on one XCD -> K/V L2 reuse.
    const int swz = (bid & 7) * 1024 + (bid >> 3);
    const int bh  = swz >> 4;
    const int qb  = swz & 15;
    const int h   = bh & (NH - 1);
    const int tid = threadIdx.x;
    const int wid = tid >> 6;
    const int lane = tid & 63;
    const int g   = lane >> 4;   // 16-lane group 0..3
    const int lr  = lane & 15;
    const int q0  = qb * 32;
    const size_t base = (size_t)bh * (NN * ND);
    const float CEXP = 0.125f * 1.44269504088896340736f;  // scale * log2(e)

    // ---- Q fragments (A-operand), kept in registers for the whole QK^T ----
    // A layout (16x16x32): row = lane&15, k = (lane>>4)*8 + j
    bf16x8 qf[2][2];
#pragma unroll
    for (int rt = 0; rt < 2; ++rt)
#pragma unroll
        for (int ks = 0; ks < 2; ++ks) {
            const float* qp = Q + base + (size_t)(q0 + rt * 16 + lr) * ND + ks * 32 + g * 8;
            fx4 a = *(const fx4*)qp;
            fx4 b = *(const fx4*)(qp + 4);
#pragma unroll
            for (int i = 0; i < 4; ++i) {
                qf[rt][ks][i]     = (__bf16)a[i];
                qf[rt][ks][4 + i] = (__bf16)b[i];
            }
        }

    // ---- QK^T: S[32][512], wave w covers 128 cols = 8 col-tiles ----
    fx4 acc[2][8];
    const fx4 vzero = {0.f, 0.f, 0.f, 0.f};
#pragma unroll
    for (int rt = 0; rt < 2; ++rt)
#pragma unroll
        for (int ct = 0; ct < 8; ++ct) acc[rt][ct] = vzero;

    const int wbase = wid * 128;
#pragma unroll
    for (int ct = 0; ct < 8; ++ct) {
        const int n = wbase + ct * 16 + lr;
        const int pid = pos_ids[h * NN + n];
        const float* kr = K + base + (size_t)n * ND;
        const float* pr = pkt + (size_t)pid * ND;
        bf16x8 bf[2];
#pragma unroll
        for (int ks = 0; ks < 2; ++ks) {
            fx4 k0 = *(const fx4*)(kr + ks * 32 + g * 8);
            fx4 k1 = *(const fx4*)(kr + ks * 32 + g * 8 + 4);
            fx4 p0 = *(const fx4*)(pr + ks * 32 + g * 8);
            fx4 p1 = *(const fx4*)(pr + ks * 32 + g * 8 + 4);
#pragma unroll
            for (int i = 0; i < 4; ++i) {
                bf[ks][i]     = (__bf16)(k0[i] + p0[i]);
                bf[ks][4 + i] = (__bf16)(k1[i] + p1[i]);
            }
        }
#pragma unroll
        for (int rt = 0; rt < 2; ++rt)
#pragma unroll
            for (int ks = 0; ks < 2; ++ks)
                acc[rt][ct] = __builtin_amdgcn_mfma_f32_16x16x32_bf16(
                    qf[rt][ks], bf[ks], acc[rt][ct], 0, 0, 0);
    }

    // ---- softmax over the full 512 cols ----
    // C/D layout: col = lane&15, row = (lane>>4)*4 + reg  [m89-verified]
    float fm[2][4], rs[2][4];
#pragma unroll
    for (int rt = 0; rt < 2; ++rt)
#pragma unroll
        for (int r = 0; r < 4; ++r) {
            float m = acc[rt][0][r];
#pragma unroll
            for (int ct = 1; ct < 8; ++ct) m = fmaxf(m, acc[rt][ct][r]);
#pragma unroll
            for (int off = 1; off < 16; off <<= 1) m = fmaxf(m, __shfl_xor(m, off));
            if (lr == 0) redA[rt * 16 + g * 4 + r][wid] = m;
        }
    __syncthreads();
#pragma unroll
    for (int rt = 0; rt < 2; ++rt)
#pragma unroll
        for (int r = 0; r < 4; ++r) {
            fx4 v = *(const fx4*)redA[rt * 16 + g * 4 + r];
            fm[rt][r] = fmaxf(fmaxf(v[0], v[1]), fmaxf(v[2], v[3]));
        }
#pragma unroll
    for (int rt = 0; rt < 2; ++rt)
#pragma unroll
        for (int r = 0; r < 4; ++r) {
            float s = 0.f;
#pragma unroll
            for (int ct = 0; ct < 8; ++ct) {
                float p = exp2f((acc[rt][ct][r] - fm[rt][r]) * CEXP);
                acc[rt][ct][r] = p;
                s += p;
            }
#pragma unroll
            for (int off = 1; off < 16; off <<= 1) s += __shfl_xor(s, off);
            if (lr == 0) redB[rt * 16 + g * 4 + r][wid] = s;
        }
    __syncthreads();
#pragma unroll
    for (int rt = 0; rt < 2; ++rt)
#pragma unroll
        for (int r = 0; r < 4; ++r) {
            fx4 v = *(const fx4*)redB[rt * 16 + g * 4 + r];
            rs[rt][r] = 1.0f / (v[0] + v[1] + v[2] + v[3]);
        }

    // ---- write normalized P (bf16) to LDS ----
#pragma unroll
    for (int rt = 0; rt < 2; ++rt)
#pragma unroll
        for (int ct = 0; ct < 8; ++ct)
#pragma unroll
            for (int r = 0; r < 4; ++r)
                Plds[rt * 16 + g * 4 + r][wbase + ct * 16 + lr] =
                    (__bf16)(acc[rt][ct][r] * rs[rt][r]);
    __syncthreads();

    // ---- attn output: coalesced fp32 stream from Plds ----
    {
        const int row = tid >> 3;
        const int c8  = (tid & 7) * 8;
        const size_t arow = ((size_t)bh * NN + q0 + row) * NN;
#pragma unroll
        for (int j = 0; j < 8; ++j) {
            bf16x8 p = *(const bf16x8*)&Plds[row][j * 64 + c8];
            fx4 o0, o1;
#pragma unroll
            for (int i = 0; i < 4; ++i) { o0[i] = (float)p[i]; o1[i] = (float)p[4 + i]; }
            *(fx4*)&attn_out[arow + j * 64 + c8]     = o0;
            *(fx4*)&attn_out[arow + j * 64 + c8 + 4] = o1;
        }
    }

    // ---- PV: context[32][64] = P @ V', V' staged transposed per 64-row chunk ----
    fx4 accp[2];
    accp[0] = vzero; accp[1] = vzero;
    const int rtp = wid >> 1;
    const int cb  = (wid & 1) * 32;
    const int nloc = tid >> 2;
    const int d0   = (tid & 3) * 16;
#pragma unroll 1
    for (int c = 0; c < 8; ++c) {
        __syncthreads();  // vt safe to overwrite (and Plds visible on c=0 path)
        {
            const int ng = c * 64 + nloc;
            const int pidv = pos_ids[h * NN + ng];
            const float* vr = V + base + (size_t)ng * ND + d0;
            const float* pr = pvt + (size_t)pidv * ND + d0;
#pragma unroll
            for (int q4 = 0; q4 < 4; ++q4) {
                fx4 v = *(const fx4*)(vr + q4 * 4);
                fx4 p = *(const fx4*)(pr + q4 * 4);
#pragma unroll
                for (int i = 0; i < 4; ++i)
                    vt[d0 + q4 * 4 + i][nloc] = (__bf16)(v[i] + p[i]);
            }
        }
        __syncthreads();
#pragma unroll
        for (int ks = 0; ks < 2; ++ks) {
            bf16x8 pa = *(const bf16x8*)&Plds[rtp * 16 + lr][c * 64 + ks * 32 + g * 8];
#pragma unroll
            for (int ctd = 0; ctd < 2; ++ctd) {
                bf16x8 vb = *(const bf16x8*)&vt[cb + ctd * 16 + lr][ks * 32 + g * 8];
                accp[ctd] = __builtin_amdgcn_mfma_f32_16x16x32_bf16(pa, vb, accp[ctd], 0, 0, 0);
            }
        }
    }

    // ---- context store ----
#pragma unroll
    for (int ctd = 0; ctd < 2; ++ctd)
#pragma unroll
        for (int r = 0; r < 4; ++r) {
            const int row = rtp * 16 + g * 4 + r;
            ctx_out[((size_t)bh * NN + q0 + row) * ND + cb + ctd * 16 + lr] = accp[ctd][r];
        }
}

extern "C" void kernel_launch(void* const* d_in, const int* in_sizes, int n_in,
                              void* d_out, int out_size, void* d_ws, size_t ws_size,
                              hipStream_t stream) {
    const float* Q   = (const float*)d_in[0];
    const float* K   = (const float*)d_in[1];
    const float* V   = (const float*)d_in[2];
    const int*   pid = (const int*)d_in[3];
    const float* pkt = (const float*)d_in[4];
    const float* pvt = (const float*)d_in[5];
    float* ctx  = (float*)d_out;
    float* attn = ctx + (size_t)NB * NH * NN * ND;  // context first, then attn

    dim3 grid(NB * NH * (NN / 32));  // 8192 blocks
    dim3 block(256);
    hipLaunchKernelGGL(attn_fused, grid, block, 0, stream,
                       Q, K, V, pid, pkt, pvt, ctx, attn);
}